// Round 2
// baseline (672.882 us; speedup 1.0000x reference)
//
#include <hip/hip_runtime.h>
#include <stdint.h>

// Problem constants (must match reference)
#define B_DIM 16
#define S_DIM 512
#define N_HASH 8
#define M_BLOOM 4096
#define W_WIN 2
#define K_BLOCKS (2 * W_WIN + 1)                       // 5
#define OUT_ELEMS (B_DIM * K_BLOCKS * M_BLOOM * S_DIM) // 167,772,160 floats

// Per-block slab: 64 m-rows of one batch, all 5 shift-blocks.
#define M_CHUNK 64
#define TILE_STRIDE 520                 // 4B guard + 512 data + 4B guard
#define TILE_BYTES (M_CHUNK * TILE_STRIDE)  // 33,280 B -> 4 blocks/CU (133 KB LDS)
#define THREADS 512                     // 8 waves/block * 4 blocks = 32 waves/CU

typedef float fx4 __attribute__((ext_vector_type(4)));

// One kernel, write-once, no global atomics.
//   out[b, k*M + m, s] = #{n : hashes[b, s + k - W, n] % M == m}, 0 if s+k-W OOB.
// Block = (b, m-chunk of 64). LDS holds uint8 counts tile[m][s] with 4-byte
// zero guards each side so the +/-2 shifted reads in phase 3 need no bounds
// checks (OOB s_in lands in a zeroed guard byte).
//
// v2 lesson: phase 3 is STORE-bound (identical dur_us across two very
// different phase-3 bodies). This version doubles occupancy (16 -> 32
// waves/CU) to double outstanding-store depth: 512-thread blocks, same
// grid, same LDS, __launch_bounds__(512,8) to pin VGPR<=64.
__global__ __launch_bounds__(THREADS, 8) void bloom_window_kernel(
    const int* __restrict__ hashes, float* __restrict__ out) {
    __shared__ __align__(16) uint32_t tile32[TILE_BYTES / 4];
    uint8_t* tile = (uint8_t*)tile32;

    const int tid = threadIdx.x;
    const int b = blockIdx.x >> 6;          // 64 chunks per batch
    const int chunk = blockIdx.x & 63;
    const int m0 = chunk * M_CHUNK;

    // Phase 1: zero the tile (incl. guards), 16 B per op. 2080 uint4 / 512 thr.
    uint4* t4 = (uint4*)tile32;
    for (int i = tid; i < TILE_BYTES / 16; i += THREADS)
        t4[i] = make_uint4(0u, 0u, 0u, 0u);
    __syncthreads();

    // Phase 2: histogram. Thread owns s-column s = tid -> no LDS write
    // collisions (DS has native byte enables; different bytes of one word
    // from different lanes are safe). 2 x int4 coalesced loads per thread.
    const int4* hp = (const int4*)hashes;
    {
        const int s = tid;
        const int4 h01 = hp[(b * S_DIM + s) * 2 + 0];
        const int4 h23 = hp[(b * S_DIM + s) * 2 + 1];
        const int hv[8] = {h01.x, h01.y, h01.z, h01.w,
                           h23.x, h23.y, h23.z, h23.w};
#pragma unroll
        for (int n = 0; n < N_HASH; ++n) {
            const int m = hv[n] & (M_BLOOM - 1);
            const unsigned ml = (unsigned)(m - m0);
            if (ml < M_CHUNK) {
                tile[ml * TILE_STRIDE + 4 + s] += 1;
            }
        }
    }
    __syncthreads();

    // Phase 3: k-shared streaming. j fixed per thread (512 % 128 == 0), m
    // steps by 4 (quarter mq = tid>>7). For each (m, j) read the 3 LDS words
    // covering bytes [4j-2 .. 4j+9] ONCE and emit all 5 shifted float4
    // outputs via constant-shift funnel merges. Wave lanes have consecutive
    // j -> stride-1 LDS words (conflict-free) and 1 KB-contiguous
    // nontemporal dwordx4 stores per k.
    const int j = tid & 127;         // float4 index along s
    const int mq = tid >> 7;         // 0..3
    fx4* out4 = (fx4*)out;

    // word index of byte A = m*520 + 4j (A is 4-aligned)
    const uint32_t* wp0 = tile32 + mq * (TILE_STRIDE / 4) + j;
    // out row (k=0) = (b*5 + 0)*M + m0 + m; 128 float4 per row
    const size_t obase0 =
        ((size_t)(b * K_BLOCKS) * M_BLOOM + m0 + mq) * (S_DIM / 4) + j;

#pragma unroll 4
    for (int it = 0; it < M_CHUNK / 4; ++it) {
        const uint32_t* wp = wp0 + it * (4 * TILE_STRIDE / 4);
        const uint32_t w0 = wp[0];   // bytes A   .. A+3
        const uint32_t w1 = wp[1];   // bytes A+4 .. A+7
        const uint32_t w2 = wp[2];   // bytes A+8 .. A+11
        const size_t ob = obase0 + (size_t)(4 * it) * (S_DIM / 4);

        // packed counts for k = 0..4: bytes [A+2+k .. A+5+k]
        uint32_t p[K_BLOCKS];
        p[0] = (w0 >> 16) | (w1 << 16);
        p[1] = (w0 >> 24) | (w1 << 8);
        p[2] = w1;
        p[3] = (w1 >> 8) | (w2 << 24);
        p[4] = (w1 >> 16) | (w2 << 16);

#pragma unroll
        for (int k = 0; k < K_BLOCKS; ++k) {
            fx4 v;
            v.x = (float)(p[k] & 0xffu);
            v.y = (float)((p[k] >> 8) & 0xffu);
            v.z = (float)((p[k] >> 16) & 0xffu);
            v.w = (float)(p[k] >> 24);
            __builtin_nontemporal_store(
                v, &out4[ob + (size_t)k * (M_BLOOM * (S_DIM / 4))]);
        }
    }
}

extern "C" void kernel_launch(void* const* d_in, const int* in_sizes, int n_in,
                              void* d_out, int out_size, void* d_ws, size_t ws_size,
                              hipStream_t stream) {
    const int* hashes = (const int*)d_in[0];
    float* out = (float*)d_out;

    // 16 batches x 64 m-chunks = 1024 blocks of 512 threads;
    // 33 KB LDS -> 4 blocks/CU -> 32 waves/CU (100% occupancy).
    bloom_window_kernel<<<B_DIM * (M_BLOOM / M_CHUNK), THREADS, 0, stream>>>(hashes, out);
}

// Round 3
// 647.099 us; speedup vs baseline: 1.0398x; 1.0398x over previous
//
#include <hip/hip_runtime.h>
#include <stdint.h>

// Problem constants (must match reference)
#define B_DIM 16
#define S_DIM 512
#define N_HASH 8
#define M_BLOOM 4096
#define W_WIN 2
#define K_BLOCKS (2 * W_WIN + 1)                       // 5
#define OUT_ELEMS (B_DIM * K_BLOCKS * M_BLOOM * S_DIM) // 167,772,160 floats

// Per-block slab: 64 m-rows of one batch, all 5 shift-blocks.
#define M_CHUNK 64
#define TILE_STRIDE 520                 // 4B guard + 512 data + 4B guard
#define TILE_BYTES (M_CHUNK * TILE_STRIDE)  // 33,280 B -> 4 blocks/CU

typedef float fx4 __attribute__((ext_vector_type(4)));

// One kernel, write-once, no global atomics.
//   out[b, k*M + m, s] = #{n : hashes[b, s + k - W, n] % M == m}, 0 if s+k-W OOB.
// Block = (b, m-chunk of 64). LDS holds uint8 counts tile[m][s] with 4-byte
// zero guards each side so the +/-2 shifted reads in phase 3 need no bounds
// checks (OOB s_in lands in a zeroed guard byte).
//
// v3 lesson: phase-3 compute cost (v1) and occupancy (v2) are both neutral
// -> kernel is bound by HBM WRITE locality, not issue rate. v3 hoists k to
// the OUTER phase-3 loop: each wave writes one sequential sweep per 8 MB
// k-region (1 active write stream/wave) instead of round-robining 5 streams
// 8 MB apart. Same addresses/values, different order only.
__global__ __launch_bounds__(256) void bloom_window_kernel(
    const int* __restrict__ hashes, float* __restrict__ out) {
    __shared__ __align__(16) uint32_t tile32[TILE_BYTES / 4];
    uint8_t* tile = (uint8_t*)tile32;

    const int tid = threadIdx.x;
    const int b = blockIdx.x >> 6;          // 64 chunks per batch
    const int chunk = blockIdx.x & 63;
    const int m0 = chunk * M_CHUNK;

    // Phase 1: zero the tile (incl. guards), 16 B per op.
    uint4* t4 = (uint4*)tile32;
    for (int i = tid; i < TILE_BYTES / 16; i += 256)
        t4[i] = make_uint4(0u, 0u, 0u, 0u);
    __syncthreads();

    // Phase 2: histogram. Thread owns s-columns {2*tid, 2*tid+1} -> no LDS
    // write collisions (DS has native byte enables; different bytes of one
    // word from different lanes are safe).
    const int4* hp = (const int4*)hashes;
#pragma unroll
    for (int ss = 0; ss < 2; ++ss) {
        const int s = 2 * tid + ss;
        const int4 h01 = hp[(b * S_DIM + s) * 2 + 0];
        const int4 h23 = hp[(b * S_DIM + s) * 2 + 1];
        const int hv[8] = {h01.x, h01.y, h01.z, h01.w,
                           h23.x, h23.y, h23.z, h23.w};
#pragma unroll
        for (int n = 0; n < N_HASH; ++n) {
            const int m = hv[n] & (M_BLOOM - 1);
            const unsigned ml = (unsigned)(m - m0);
            if (ml < M_CHUNK) {
                tile[ml * TILE_STRIDE + 4 + s] += 1;
            }
        }
    }
    __syncthreads();

    // Phase 3: k-OUTER streaming. j fixed per thread (256 % 128 == 0), m
    // steps by 2 within each k-sweep. For float4-column j of row m, the
    // bytes needed for shift k are [m*520 + 4j + 2+k .. +5+k]; with k a
    // compile-time constant per unrolled outer iteration, only the 1-2
    // needed LDS words are read (dead reads DCE'd). Wave lanes have
    // consecutive j -> stride-1 LDS words (conflict-free) and 1 KB
    // contiguous nontemporal dwordx4 stores marching sequentially through
    // ONE 8 MB k-region at a time.
    const int j = tid & 127;         // float4 index along s
    const int mb = tid >> 7;         // 0 or 1
    fx4* out4 = (fx4*)out;

    // word index of byte A = m*520 + 4j (A is 4-aligned)
    const uint32_t* wp0 = tile32 + mb * (TILE_STRIDE / 4) + j;
    // out row (k=0) = (b*5 + 0)*M + m0 + m; 128 float4 per row
    const size_t obase0 =
        ((size_t)(b * K_BLOCKS) * M_BLOOM + m0 + mb) * (S_DIM / 4) + j;

#pragma unroll
    for (int k = 0; k < K_BLOCKS; ++k) {
        const size_t okbase = obase0 + (size_t)k * (M_BLOOM * (S_DIM / 4));
#pragma unroll 4
        for (int it = 0; it < M_CHUNK / 2; ++it) {
            const uint32_t* wp = wp0 + it * (2 * TILE_STRIDE / 4);
            const uint32_t w0 = wp[0];   // bytes A   .. A+3
            const uint32_t w1 = wp[1];   // bytes A+4 .. A+7
            const uint32_t w2 = wp[2];   // bytes A+8 .. A+11

            // packed counts for this k: bytes [A+2+k .. A+5+k]
            const uint32_t p =
                (k == 0) ? ((w0 >> 16) | (w1 << 16)) :
                (k == 1) ? ((w0 >> 24) | (w1 << 8))  :
                (k == 2) ? w1                        :
                (k == 3) ? ((w1 >> 8) | (w2 << 24))  :
                           ((w1 >> 16) | (w2 << 16));

            fx4 v;
            v.x = (float)(p & 0xffu);
            v.y = (float)((p >> 8) & 0xffu);
            v.z = (float)((p >> 16) & 0xffu);
            v.w = (float)(p >> 24);
            __builtin_nontemporal_store(
                v, &out4[okbase + (size_t)(2 * it) * (S_DIM / 4)]);
        }
    }
}

extern "C" void kernel_launch(void* const* d_in, const int* in_sizes, int n_in,
                              void* d_out, int out_size, void* d_ws, size_t ws_size,
                              hipStream_t stream) {
    const int* hashes = (const int*)d_in[0];
    float* out = (float*)d_out;

    // 16 batches x 64 m-chunks = 1024 blocks; 33 KB LDS -> 4 blocks/CU.
    bloom_window_kernel<<<B_DIM * (M_BLOOM / M_CHUNK), 256, 0, stream>>>(hashes, out);
}